// Round 7
// baseline (1030.921 us; speedup 1.0000x reference)
//
#include <hip/hip_runtime.h>
#include <hip/hip_bf16.h>

#define B_ 256
#define T_ 512
#define I_ 128
#define H_ 256

typedef __bf16 bf16x8 __attribute__((ext_vector_type(8)));
typedef float  f32x4  __attribute__((ext_vector_type(4)));
typedef unsigned short u16;
typedef unsigned int   u32;

union U16x8Cast { uint4 v; bf16x8 b; };

__device__ inline u16 f2b(float f) {
    union { __bf16 h; u16 u; } c; c.h = (__bf16)f; return c.u;
}
__device__ inline bf16x8 pack8(float4 lo, float4 hi) {
    bf16x8 f;
    f[0]=(__bf16)lo.x; f[1]=(__bf16)lo.y; f[2]=(__bf16)lo.z; f[3]=(__bf16)lo.w;
    f[4]=(__bf16)hi.x; f[5]=(__bf16)hi.y; f[6]=(__bf16)hi.z; f[7]=(__bf16)hi.w;
    return f;
}
__device__ inline uint2 pack4(float a, float b, float c, float d) {
    uint2 p;
    p.x = (u32)f2b(a) | ((u32)f2b(b) << 16);
    p.y = (u32)f2b(c) | ((u32)f2b(d) << 16);
    return p;
}
__device__ inline f32x4 b4_to_f32x4(uint2 u) {
    f32x4 r;
    r[0] = __uint_as_float(u.x << 16);
    r[1] = __uint_as_float(u.x & 0xFFFF0000u);
    r[2] = __uint_as_float(u.y << 16);
    r[3] = __uint_as_float(u.y & 0xFFFF0000u);
    return r;
}
__device__ inline float fast_tanh(float x) {
    float e = __expf(2.f * x);
    float r = 1.f / (1.f + e);
    return 1.f - 2.f * r;
}

// Agent-scope acquire gate: spin until done-counter hits 16, then invalidate
// caches so cross-XCD xw writes are visible to our plain loads.
__device__ inline void spin_done(const u32* p) {
    while (__hip_atomic_load(p, __ATOMIC_RELAXED, __HIP_MEMORY_SCOPE_AGENT) < 16u)
        __builtin_amdgcn_s_sleep(8);
    __threadfence();   // acquire: buffer_inv so stale L2 lines are dropped
}

#define LDST 264   // u16 stride of gemm LDS tile row (528 B)

// =====================================================================
// ONE persistent kernel, 256 WGs x 512 threads (all co-resident: 8 waves,
// ~34 KB LDS, <=256 VGPR -> every CU hosts >=1 WG).
//   WG 0..15   : R4-structure MFMA scan (16 batch rows each), gated on
//                per-(t-block, group) done counters (4 gates total).
//   WG 16..255 : persistent GEMM workers; t-major tickets; device-scope
//                release publish. GEMM (~140 us) runs concurrently under
//                the scan (~590 us) -> prologue cost vanishes + chip stays
//                loaded (clock-throttle test).
// ctrl layout (zeroed via hipMemsetAsync): [0]=ticket ctr; +16: done[64]
// entries padded x16 (u32 idx (tb*16+g)*16).
// =====================================================================
__global__ __launch_bounds__(512, 2) void fused_rnn(const float* __restrict__ x,
                                                    const float* __restrict__ W_ih,
                                                    const float* __restrict__ W_hh,
                                                    const float* __restrict__ b_ih,
                                                    const float* __restrict__ b_hh,
                                                    const float* __restrict__ fc_w,
                                                    const float* __restrict__ fc_b,
                                                    float* __restrict__ out,
                                                    u32* __restrict__ ctrl,
                                                    u16* __restrict__ xw) {
    __shared__ u16 lds[64 * LDST];   // 33.8 KB, reused by both paths
    __shared__ u32 tkt;

    const int tid  = (int)threadIdx.x;
    const int wave = tid >> 6;       // 0..7
    const int lane = tid & 63;
    const int q    = lane >> 4;
    const int ml   = lane & 15;

    u32* ctr  = ctrl;
    u32* done = ctrl + 16;           // 64 entries, x16 padded

    const size_t tstride = (size_t)B_ * H_;

    if (blockIdx.x < 16) {
        // ================= SCAN (R4 structure) =================
        u16 (*hbuf)[4096] = (u16(*)[4096])lds;            // 2 x 8 KB
        float (*red)[16]  = (float(*)[16])(lds + 8192);
        const int g  = (int)blockIdx.x;
        const int b0 = g * 16;
        const int m  = ml;

        // W_hh A-frags: lane holds W_hh[n = wave*32+tau2*16+m][k = kap*32+q*8+0..7]
        bf16x8 wf[2][8];
#pragma unroll
        for (int tau2 = 0; tau2 < 2; ++tau2) {
            const float* wr = W_hh + (size_t)(wave * 32 + tau2 * 16 + m) * H_;
#pragma unroll
            for (int kap = 0; kap < 8; ++kap) {
                const int k0 = kap * 32 + q * 8;
                wf[tau2][kap] = pack8(*(const float4*)(wr + k0), *(const float4*)(wr + k0 + 4));
            }
        }

        int widx[2];
#pragma unroll
        for (int tau2 = 0; tau2 < 2; ++tau2) {
            const int nbw = wave * 32 + tau2 * 16 + q * 4;
            widx[tau2] = (nbw >> 5) * 512 + (((nbw >> 3) & 3) * 16 + m) * 8 + (nbw & 7);
        }

        {   // zero h buffer 0 (8 KB = 512 uint4)
            uint4* p = (uint4*)&hbuf[0][0];
            const uint4 z = {0u, 0u, 0u, 0u};
            p[tid] = z;
        }
        __syncthreads();

        spin_done(&done[(0 * 16 + g) * 16]);              // wait for t-block 0

        const u16* xwp = xw + (size_t)(b0 + m) * H_ + (wave * 32 + q * 4);
        f32x4 xwv[2];
        xwv[0] = b4_to_f32x4(*(const uint2*)(xwp));
        xwv[1] = b4_to_f32x4(*(const uint2*)(xwp + 16));

        int cur = 0;
        f32x4 acc[2];
        for (int t = 0; t < T_; ++t) {
            acc[0] = xwv[0];
            acc[1] = xwv[1];
            if (t + 1 < T_) {                             // prefetch next step's xw
                if (((t + 1) & 127) == 0)                 // t-block boundary gate
                    spin_done(&done[(((t + 1) >> 7) * 16 + g) * 16]);
                const u16* pt = xwp + (size_t)(t + 1) * tstride;
                xwv[0] = b4_to_f32x4(*(const uint2*)(pt));
                xwv[1] = b4_to_f32x4(*(const uint2*)(pt + 16));
            }

            const uint4* hb = (const uint4*)&hbuf[cur][0];
#pragma unroll
            for (int kap = 0; kap < 8; ++kap) {
                U16x8Cast c; c.v = hb[kap * 64 + lane];   // linear, conflict-free b128
                acc[0] = __builtin_amdgcn_mfma_f32_16x16x32_bf16(wf[0][kap], c.b, acc[0], 0, 0, 0);
                acc[1] = __builtin_amdgcn_mfma_f32_16x16x32_bf16(wf[1][kap], c.b, acc[1], 0, 0, 0);
            }

            if (t == T_ - 1) break;                       // last h feeds fc only

            u16* wb = &hbuf[cur ^ 1][0];
#pragma unroll
            for (int tau2 = 0; tau2 < 2; ++tau2) {
                uint2 pk = pack4(fast_tanh(acc[tau2][0]), fast_tanh(acc[tau2][1]),
                                 fast_tanh(acc[tau2][2]), fast_tanh(acc[tau2][3]));
                *(uint2*)(wb + widx[tau2]) = pk;
            }
            __syncthreads();
            cur ^= 1;
        }

        // fc head: out[b] = sum_n tanh(h)[n] * fc_w[n] + fc_b
        float4 fcw[2];
#pragma unroll
        for (int tau2 = 0; tau2 < 2; ++tau2)
            fcw[tau2] = *(const float4*)(fc_w + wave * 32 + tau2 * 16 + q * 4);

        float partial = 0.f;
#pragma unroll
        for (int tau2 = 0; tau2 < 2; ++tau2) {
            partial += fast_tanh(acc[tau2][0]) * fcw[tau2].x;
            partial += fast_tanh(acc[tau2][1]) * fcw[tau2].y;
            partial += fast_tanh(acc[tau2][2]) * fcw[tau2].z;
            partial += fast_tanh(acc[tau2][3]) * fcw[tau2].w;
        }
        partial += __shfl_xor(partial, 16);
        partial += __shfl_xor(partial, 32);
        __syncthreads();
        if (lane < 16) red[wave][m] = partial;
        __syncthreads();
        if (tid < 16) {
            float s = red[0][tid] + red[1][tid] + red[2][tid] + red[3][tid]
                    + red[4][tid] + red[5][tid] + red[6][tid] + red[7][tid];
            out[b0 + tid] = s + fc_b[0];
        }
    } else {
        // ================= GEMM workers =================
        const int n0w = wave * 32;

        // Resident W_ih A-frags for this wave's 32 n-rows
        bf16x8 wA[2][4];
#pragma unroll
        for (int tau2 = 0; tau2 < 2; ++tau2) {
            const float* wr = W_ih + (size_t)(n0w + tau2 * 16 + ml) * I_;
#pragma unroll
            for (int kap = 0; kap < 4; ++kap) {
                const int k0 = kap * 32 + q * 8;
                wA[tau2][kap] = pack8(*(const float4*)(wr + k0), *(const float4*)(wr + k0 + 4));
            }
        }
        float4 bias4[2];
#pragma unroll
        for (int tau2 = 0; tau2 < 2; ++tau2) {
            const int n = n0w + tau2 * 16 + q * 4;
            float4 bi = *(const float4*)(b_ih + n);
            float4 bh = *(const float4*)(b_hh + n);
            bias4[tau2] = make_float4(bi.x + bh.x, bi.y + bh.y, bi.z + bh.z, bi.w + bh.w);
        }

        for (;;) {
            if (tid == 0) tkt = atomicAdd(ctr, 1u);
            __syncthreads();
            const u32 ticket = tkt;
            __syncthreads();
            if (ticket >= 1024u) break;

            const int tb = (int)(ticket >> 8);            // t-block 0..3 (t-major!)
            const int bb = (int)(ticket & 255u);          // batch row
            const int m0 = bb * T_ + tb * 128;            // x row base

            f32x4 acc[8][2];
#pragma unroll
            for (int mt = 0; mt < 8; ++mt) { acc[mt][0] = (f32x4)0.f; acc[mt][1] = (f32x4)0.f; }

#pragma unroll
            for (int kap = 0; kap < 4; ++kap) {
                bf16x8 xB[8];
#pragma unroll
                for (int mt = 0; mt < 8; ++mt) {
                    const float* xr = x + (size_t)(m0 + mt * 16 + ml) * I_ + kap * 32 + q * 8;
                    xB[mt] = pack8(*(const float4*)xr, *(const float4*)(xr + 4));
                }
#pragma unroll
                for (int mt = 0; mt < 8; ++mt) {
                    acc[mt][0] = __builtin_amdgcn_mfma_f32_16x16x32_bf16(wA[0][kap], xB[mt], acc[mt][0], 0, 0, 0);
                    acc[mt][1] = __builtin_amdgcn_mfma_f32_16x16x32_bf16(wA[1][kap], xB[mt], acc[mt][1], 0, 0, 0);
                }
            }

            // Epilogue: 2 passes of 64 t-rows through LDS, coalesced out.
#pragma unroll
            for (int p = 0; p < 2; ++p) {
                if (p) __syncthreads();
#pragma unroll
                for (int mt = 0; mt < 4; ++mt) {
                    const int row = mt * 16 + ml;         // local t-row (C col = ml)
                    const int mg  = p * 4 + mt;
#pragma unroll
                    for (int tau2 = 0; tau2 < 2; ++tau2) {
                        uint2 pk = pack4(acc[mg][tau2][0] + bias4[tau2].x,
                                         acc[mg][tau2][1] + bias4[tau2].y,
                                         acc[mg][tau2][2] + bias4[tau2].z,
                                         acc[mg][tau2][3] + bias4[tau2].w);
                        *(uint2*)(lds + row * LDST + n0w + tau2 * 16 + q * 4) = pk;
                    }
                }
                __syncthreads();
                // copy-out: 64 rows x 512 B; 32 lanes sweep one row
#pragma unroll
                for (int s = 0; s < 2; ++s) {
                    const int rr = s * 32 + (tid >> 4);   // 0..63
                    const int c  = tid & 15;              // 16 x uint4 x2 per row
                    const uint4* srcp = (const uint4*)(lds + rr * LDST);
                    uint4* dstp = (uint4*)(xw + ((size_t)(tb * 128 + p * 64 + rr) * B_ + bb) * H_);
                    uint4 v0 = srcp[c];
                    uint4 v1 = srcp[c + 16];
                    dstp[c] = v0;
                    dstp[c + 16] = v1;
                }
            }

            __threadfence();                              // release: drain + L2 wb
            __syncthreads();
            if (tid == 0)
                __hip_atomic_fetch_add(&done[(tb * 16 + (bb >> 4)) * 16], 1u,
                                       __ATOMIC_RELEASE, __HIP_MEMORY_SCOPE_AGENT);
            __syncthreads();                              // lds reuse hazard
        }
    }
}

// =====================================================================
extern "C" void kernel_launch(void* const* d_in, const int* in_sizes, int n_in,
                              void* d_out, int out_size, void* d_ws, size_t ws_size,
                              hipStream_t stream) {
    const float* x    = (const float*)d_in[0];
    const float* W_ih = (const float*)d_in[1];
    const float* W_hh = (const float*)d_in[2];
    const float* b_ih = (const float*)d_in[3];
    const float* b_hh = (const float*)d_in[4];
    const float* fc_w = (const float*)d_in[5];
    const float* fc_b = (const float*)d_in[6];
    float* out = (float*)d_out;

    // ws: [ctrl: 8 KB (zeroed)][xw bf16 [T][B][H]: 64 MB]
    u32* ctrl  = (u32*)d_ws;
    u16* xwbuf = (u16*)((char*)d_ws + 8192);

    hipMemsetAsync(d_ws, 0, 8192, stream);
    fused_rnn<<<256, 512, 0, stream>>>(x, W_ih, W_hh, b_ih, b_hh, fc_w, fc_b,
                                       out, ctrl, xwbuf);
}

// Round 8
// 457.861 us; speedup vs baseline: 2.2516x; 2.2516x over previous
//
#include <hip/hip_runtime.h>
#include <hip/hip_bf16.h>

#define B_ 256
#define T_ 512
#define I_ 128
#define H_ 256

typedef __bf16 bf16x8 __attribute__((ext_vector_type(8)));
typedef float  f32x4  __attribute__((ext_vector_type(4)));
typedef unsigned short u16;
typedef unsigned int   u32;

union U16x8Cast { uint4 v; bf16x8 b; };

__device__ inline u16 f2b(float f) {           // fp32 -> bf16 bits (RNE)
    union { __bf16 h; u16 u; } c; c.h = (__bf16)f; return c.u;
}
__device__ inline bf16x8 pack8(float4 lo, float4 hi) {
    bf16x8 f;
    f[0]=(__bf16)lo.x; f[1]=(__bf16)lo.y; f[2]=(__bf16)lo.z; f[3]=(__bf16)lo.w;
    f[4]=(__bf16)hi.x; f[5]=(__bf16)hi.y; f[6]=(__bf16)hi.z; f[7]=(__bf16)hi.w;
    return f;
}
__device__ inline uint2 pack4(float a, float b, float c, float d) {
    uint2 p;
    p.x = (u32)f2b(a) | ((u32)f2b(b) << 16);
    p.y = (u32)f2b(c) | ((u32)f2b(d) << 16);
    return p;
}
__device__ inline f32x4 b4_to_f32x4(uint2 u) {
    f32x4 r;
    r[0] = __uint_as_float(u.x << 16);
    r[1] = __uint_as_float(u.x & 0xFFFF0000u);
    r[2] = __uint_as_float(u.y << 16);
    r[3] = __uint_as_float(u.y & 0xFFFF0000u);
    return r;
}
// tanh(x) = 1 - 2/(1+e^{2x}); v_rcp (±1 ulp) instead of the ~10-instr
// precise-div sequence the compiler emits for 1.f/x without fast-math.
__device__ inline float fast_tanh(float x) {
    float e = __expf(2.f * x);                 // v_mul + v_exp
    float d = 1.f + e;
    float r;
    asm("v_rcp_f32 %0, %1" : "=v"(r) : "v"(d));
    return fmaf(-2.f, r, 1.f);                 // x<<0 -> -1, x>>0 -> 1, no NaN
}

// LDS-drain-only workgroup barrier: does NOT wait vmcnt, so global
// prefetch loads stay in flight across the barrier (the __syncthreads
// vmcnt(0) drain was the ~900-cyc/step exposed-HBM-latency stall).
#define WG_BARRIER() asm volatile("s_waitcnt lgkmcnt(0)\n\ts_barrier" ::: "memory")

// =====================================================================
// Kernel 1 (MFMA GEMM, R5 version): xw[t][b][n] = x[bT+t,:]*W_ih[n,:]+bias
// 128-row m-tile, LDS-staged coalesced bf16 stores to [t][b][n].
// =====================================================================
#define LDST 264
__global__ __launch_bounds__(256, 2) void xw_gemm_mfma(const float* __restrict__ x,
                                                       const float* __restrict__ W_ih,
                                                       const float* __restrict__ b_ih,
                                                       const float* __restrict__ b_hh,
                                                       u16* __restrict__ xw) {
    __shared__ u16 tile[64 * LDST];

    const int tid  = (int)threadIdx.x;
    const int wave = tid >> 6;
    const int lane = tid & 63;
    const int q    = lane >> 4;
    const int ml   = lane & 15;
    const int m0   = (int)blockIdx.x * 128;
    const int b    = m0 >> 9;
    const int t0   = m0 & 511;
    const int n0   = wave * 64;

    bf16x8 wA[4][4];
#pragma unroll
    for (int tau = 0; tau < 4; ++tau) {
        const float* wr = W_ih + (size_t)(n0 + tau * 16 + ml) * I_;
#pragma unroll
        for (int kap = 0; kap < 4; ++kap) {
            const int k0 = kap * 32 + q * 8;
            wA[tau][kap] = pack8(*(const float4*)(wr + k0), *(const float4*)(wr + k0 + 4));
        }
    }

    f32x4 acc[8][4];
#pragma unroll
    for (int mt = 0; mt < 8; ++mt)
#pragma unroll
        for (int tau = 0; tau < 4; ++tau) acc[mt][tau] = (f32x4)0.f;

#pragma unroll
    for (int kap = 0; kap < 4; ++kap) {
        bf16x8 xB[8];
#pragma unroll
        for (int mt = 0; mt < 8; ++mt) {
            const float* xr = x + (size_t)(m0 + mt * 16 + ml) * I_ + kap * 32 + q * 8;
            xB[mt] = pack8(*(const float4*)xr, *(const float4*)(xr + 4));
        }
#pragma unroll
        for (int mt = 0; mt < 8; ++mt)
#pragma unroll
            for (int tau = 0; tau < 4; ++tau)
                acc[mt][tau] = __builtin_amdgcn_mfma_f32_16x16x32_bf16(
                    wA[tau][kap], xB[mt], acc[mt][tau], 0, 0, 0);
    }

    float4 bias4[4];
#pragma unroll
    for (int tau = 0; tau < 4; ++tau) {
        const int n = n0 + tau * 16 + q * 4;
        float4 bi = *(const float4*)(b_ih + n);
        float4 bh = *(const float4*)(b_hh + n);
        bias4[tau] = make_float4(bi.x + bh.x, bi.y + bh.y, bi.z + bh.z, bi.w + bh.w);
    }

#pragma unroll
    for (int p = 0; p < 2; ++p) {
        if (p) __syncthreads();
#pragma unroll
        for (int mt = 0; mt < 4; ++mt) {
            const int row = mt * 16 + ml;
            const int mg  = p * 4 + mt;
#pragma unroll
            for (int tau = 0; tau < 4; ++tau) {
                uint2 pk = pack4(acc[mg][tau][0] + bias4[tau].x,
                                 acc[mg][tau][1] + bias4[tau].y,
                                 acc[mg][tau][2] + bias4[tau].z,
                                 acc[mg][tau][3] + bias4[tau].w);
                *(uint2*)(tile + row * LDST + n0 + tau * 16 + q * 4) = pk;
            }
        }
        __syncthreads();
#pragma unroll
        for (int s = 0; s < 4; ++s) {
            const int rr = s * 16 + (tid >> 4);
            const int c  = tid & 15;
            const uint4* srcp = (const uint4*)(tile + rr * LDST);
            uint4* dstp = (uint4*)(xw + ((size_t)(t0 + p * 64 + rr) * B_ + b) * H_);
            uint4 v0 = srcp[c];
            uint4 v1 = srcp[c + 16];
            dstp[c] = v0;
            dstp[c + 16] = v1;
        }
    }
}

// =====================================================================
// Kernel 2 (MFMA scan) — R4 structure (best measured) + three fixes:
//  1. lgkm-only barrier (no vmcnt drain of the xw prefetch)
//  2. t-loop unrolled x2 with ALTERNATING prefetch regs pfA/pfB (no
//     register copies -> true 2-step issue-to-use distance, HBM hidden)
//  3. v_rcp-based tanh (kills precise-div sequence)
// 16 WGs x 512 thr (8 waves, 2/SIMD). Wave owns 32 H-rows as inline-packed
// A-frags. h ping-pongs in LDS in B-frag order (linear b128, conflict-free).
// =====================================================================
__global__ __launch_bounds__(512, 2) void rnn_scan_mfma(const u16* __restrict__ xw,
                                                        const float* __restrict__ W_hh,
                                                        const float* __restrict__ fc_w,
                                                        const float* __restrict__ fc_b,
                                                        float* __restrict__ out) {
    __shared__ __attribute__((aligned(16))) u16 hbuf[2][4096];  // 2 x 8 KB
    __shared__ float red[8][16];

    const int tid  = (int)threadIdx.x;
    const int wave = tid >> 6;          // 0..7
    const int lane = tid & 63;
    const int q    = lane >> 4;
    const int m    = lane & 15;
    const int b0   = (int)blockIdx.x * 16;

    // W_hh A-frags: lane holds W_hh[n = wave*32+tau2*16+m][k = kap*32+q*8+0..7]
    bf16x8 wf[2][8];
#pragma unroll
    for (int tau2 = 0; tau2 < 2; ++tau2) {
        const float* wr = W_hh + (size_t)(wave * 32 + tau2 * 16 + m) * H_;
#pragma unroll
        for (int kap = 0; kap < 8; ++kap) {
            const int k0 = kap * 32 + q * 8;
            wf[tau2][kap] = pack8(*(const float4*)(wr + k0), *(const float4*)(wr + k0 + 4));
        }
    }

    // LDS write indices (u16 units) for C -> B-frag relayout
    int widx[2];
#pragma unroll
    for (int tau2 = 0; tau2 < 2; ++tau2) {
        const int nbw = wave * 32 + tau2 * 16 + q * 4;
        widx[tau2] = (nbw >> 5) * 512 + (((nbw >> 3) & 3) * 16 + m) * 8 + (nbw & 7);
    }

    {   // zero h buffer 0 (8 KB = 512 uint4)
        uint4* p = (uint4*)&hbuf[0][0];
        const uint4 z = {0u, 0u, 0u, 0u};
        p[tid] = z;
    }
    WG_BARRIER();

    // xw ([t][b][n]): lane reads 2 x uint2 per step.
    const u16* xwp = xw + (size_t)(b0 + m) * H_ + (wave * 32 + q * 4);
    const size_t tstride = (size_t)B_ * H_;

    uint2 pfA[2], pfB[2];                              // alternating, never copied
    pfA[0] = *(const uint2*)(xwp);
    pfA[1] = *(const uint2*)(xwp + 16);
    pfB[0] = *(const uint2*)(xwp + tstride);
    pfB[1] = *(const uint2*)(xwp + tstride + 16);

    int cur = 0;
    f32x4 acc[2];
    for (int tt = 0; tt < T_ / 2; ++tt) {
        // ---------- step A: t = 2*tt (even, never last) ----------
        {
            const int t = 2 * tt;
            acc[0] = b4_to_f32x4(pfA[0]);
            acc[1] = b4_to_f32x4(pfA[1]);
            if (t + 2 < T_) {                          // reload pfA for t+2
                const u16* pt = xwp + (size_t)(t + 2) * tstride;
                pfA[0] = *(const uint2*)(pt);
                pfA[1] = *(const uint2*)(pt + 16);
            }
            const uint4* hb = (const uint4*)&hbuf[cur][0];
#pragma unroll
            for (int kap = 0; kap < 8; ++kap) {
                U16x8Cast c; c.v = hb[kap * 64 + lane];
                acc[0] = __builtin_amdgcn_mfma_f32_16x16x32_bf16(wf[0][kap], c.b, acc[0], 0, 0, 0);
                acc[1] = __builtin_amdgcn_mfma_f32_16x16x32_bf16(wf[1][kap], c.b, acc[1], 0, 0, 0);
            }
            u16* wb = &hbuf[cur ^ 1][0];
#pragma unroll
            for (int tau2 = 0; tau2 < 2; ++tau2) {
                uint2 pk = pack4(fast_tanh(acc[tau2][0]), fast_tanh(acc[tau2][1]),
                                 fast_tanh(acc[tau2][2]), fast_tanh(acc[tau2][3]));
                *(uint2*)(wb + widx[tau2]) = pk;
            }
            WG_BARRIER();
            cur ^= 1;
        }
        // ---------- step B: t = 2*tt+1 (t = T_-1 on the last iter) ----------
        {
            const int t = 2 * tt + 1;
            acc[0] = b4_to_f32x4(pfB[0]);
            acc[1] = b4_to_f32x4(pfB[1]);
            if (t + 2 < T_) {                          // reload pfB for t+2
                const u16* pt = xwp + (size_t)(t + 2) * tstride;
                pfB[0] = *(const uint2*)(pt);
                pfB[1] = *(const uint2*)(pt + 16);
            }
            const uint4* hb = (const uint4*)&hbuf[cur][0];
#pragma unroll
            for (int kap = 0; kap < 8; ++kap) {
                U16x8Cast c; c.v = hb[kap * 64 + lane];
                acc[0] = __builtin_amdgcn_mfma_f32_16x16x32_bf16(wf[0][kap], c.b, acc[0], 0, 0, 0);
                acc[1] = __builtin_amdgcn_mfma_f32_16x16x32_bf16(wf[1][kap], c.b, acc[1], 0, 0, 0);
            }
            if (t != T_ - 1) {                         // last h feeds fc only
                u16* wb = &hbuf[cur ^ 1][0];
#pragma unroll
                for (int tau2 = 0; tau2 < 2; ++tau2) {
                    uint2 pk = pack4(fast_tanh(acc[tau2][0]), fast_tanh(acc[tau2][1]),
                                     fast_tanh(acc[tau2][2]), fast_tanh(acc[tau2][3]));
                    *(uint2*)(wb + widx[tau2]) = pk;
                }
                WG_BARRIER();
                cur ^= 1;
            }
        }
    }

    // fc head: out[b] = sum_n tanh(h)[n] * fc_w[n] + fc_b
    float4 fcw[2];
#pragma unroll
    for (int tau2 = 0; tau2 < 2; ++tau2)
        fcw[tau2] = *(const float4*)(fc_w + wave * 32 + tau2 * 16 + q * 4);

    float partial = 0.f;
#pragma unroll
    for (int tau2 = 0; tau2 < 2; ++tau2) {
        partial += fast_tanh(acc[tau2][0]) * fcw[tau2].x;
        partial += fast_tanh(acc[tau2][1]) * fcw[tau2].y;
        partial += fast_tanh(acc[tau2][2]) * fcw[tau2].z;
        partial += fast_tanh(acc[tau2][3]) * fcw[tau2].w;
    }
    partial += __shfl_xor(partial, 16);
    partial += __shfl_xor(partial, 32);
    __syncthreads();
    if (lane < 16) red[wave][m] = partial;
    __syncthreads();
    if (tid < 16) {
        float s = red[0][tid] + red[1][tid] + red[2][tid] + red[3][tid]
                + red[4][tid] + red[5][tid] + red[6][tid] + red[7][tid];
        out[b0 + tid] = s + fc_b[0];
    }
}

// =====================================================================
extern "C" void kernel_launch(void* const* d_in, const int* in_sizes, int n_in,
                              void* d_out, int out_size, void* d_ws, size_t ws_size,
                              hipStream_t stream) {
    const float* x    = (const float*)d_in[0];
    const float* W_ih = (const float*)d_in[1];
    const float* W_hh = (const float*)d_in[2];
    const float* b_ih = (const float*)d_in[3];
    const float* b_hh = (const float*)d_in[4];
    const float* fc_w = (const float*)d_in[5];
    const float* fc_b = (const float*)d_in[6];
    float* out = (float*)d_out;

    u16* xwbuf = (u16*)d_ws;                           // 64 MB bf16 [T][B][H]
    xw_gemm_mfma<<<(B_ * T_) / 128, 256, 0, stream>>>(x, W_ih, b_ih, b_hh, xwbuf);
    rnn_scan_mfma<<<B_ / 16, 512, 0, stream>>>(xwbuf, W_hh, fc_w, fc_b, out);
}